// Round 6
// baseline (183.241 us; speedup 1.0000x reference)
//
#include <hip/hip_runtime.h>

#define D 32

// ---- fast-path geometry (requires N == 16384) ----
#define NB_C     8          // coarse bins: node >> 11
#define FPERC    128        // fine bins per coarse bin
#define NB_F     1024       // fine bins: node >> 4  (16 nodes each)
#define CCAP     524288     // entries per coarse list (mean 131K, 4x margin)
#define FCAP     4096       // entries per fine list  (mean 1024, 4x margin)
#define SPILLCAP 8192
#define A_EPB    4096       // edges per block, K1
#define A_CAP    512        // per-wave per-coarse-bin LDS bucket (mean 256)
#define A2_EPB   8192       // entries per block, K2
#define A2_CAP   128        // per-fine-bin LDS bucket (mean 64)
#define GCAP     256        // per-node neighbor cap for fast extraction

// ===========================================================================
// K1: coarse-bin directed edge entries (node:14 | nbr:14) into 8 global lists.
// LDS-staged per-wave buckets; ONE flush at end -> coalesced stores, ~32
// global atomics per block instead of per-entry.
// ===========================================================================
__global__ __launch_bounds__(256) void gnn_bin_coarse(
        const int* __restrict__ src, const int* __restrict__ dst, int E,
        unsigned int* __restrict__ clist, int* __restrict__ ccnt,
        unsigned int* __restrict__ spill, int* __restrict__ spillcnt) {
    __shared__ unsigned int buf[4][NB_C][A_CAP];   // 64 KB
    __shared__ int bcnt[4][NB_C];
    int t = threadIdx.x, wv = t >> 6, lane = t & 63;
    if (lane < NB_C) bcnt[wv][lane] = 0;
    __syncthreads();

    int base = blockIdx.x * A_EPB;
    int lim  = min(base + A_EPB, E);
    for (int e = base + t; e < lim; e += 256) {
        int s = src[e], d2 = dst[e];
        unsigned int e1 = ((unsigned int)d2 << 14) | (unsigned int)s;  // for node d2
        unsigned int e2 = ((unsigned int)s  << 14) | (unsigned int)d2; // for node s
        int b1 = d2 >> 11, b2 = s >> 11;
        int p1 = atomicAdd(&bcnt[wv][b1], 1);
        if (p1 < A_CAP) buf[wv][b1][p1] = e1;
        else { int sp = atomicAdd(spillcnt, 1); if (sp < SPILLCAP) spill[sp] = e1; }
        int p2 = atomicAdd(&bcnt[wv][b2], 1);
        if (p2 < A_CAP) buf[wv][b2][p2] = e2;
        else { int sp = atomicAdd(spillcnt, 1); if (sp < SPILLCAP) spill[sp] = e2; }
    }
    __syncthreads();

    // flush: each wave flushes its own 8 buckets, 64-lane coalesced copies
    for (int b = 0; b < NB_C; ++b) {
        int c = bcnt[wv][b]; if (c > A_CAP) c = A_CAP;
        if (c == 0) continue;
        int gbase = 0;
        if (lane == 0) gbase = atomicAdd(&ccnt[b], c);
        gbase = __shfl(gbase, 0, 64);
        for (int i = lane; i < c; i += 64) {
            int pos = gbase + i;
            unsigned int v = buf[wv][b][i];
            if (pos < CCAP) clist[(size_t)b * CCAP + pos] = v;
            else { int sp = atomicAdd(spillcnt, 1); if (sp < SPILLCAP) spill[sp] = v; }
        }
    }
}

// ===========================================================================
// K2: redistribute each coarse list into 128 fine bins (16 nodes each).
// Grid = NB_C * 64 slices; blocks beyond a bin's count exit early.
// ===========================================================================
__global__ __launch_bounds__(256) void gnn_bin_fine(
        const unsigned int* __restrict__ clist, const int* __restrict__ ccnt,
        unsigned int* __restrict__ flist, int* __restrict__ fcnt,
        unsigned int* __restrict__ spill, int* __restrict__ spillcnt) {
    int cb = blockIdx.x & (NB_C - 1);
    int slice = blockIdx.x >> 3;
    int cnt = ccnt[cb]; if (cnt > CCAP) cnt = CCAP;
    int base = slice * A2_EPB;
    if (base >= cnt) return;
    int lim = min(base + A2_EPB, cnt);

    __shared__ unsigned int buf[FPERC][A2_CAP];    // 64 KB
    __shared__ int bcnt[FPERC];
    int t = threadIdx.x;
    if (t < FPERC) bcnt[t] = 0;
    __syncthreads();

    const unsigned int* cl = clist + (size_t)cb * CCAP;
    for (int i = base + t; i < lim; i += 256) {
        unsigned int en = cl[i];
        int fb = (en >> 18) & (FPERC - 1);         // (node >> 4) & 127
        int p = atomicAdd(&bcnt[fb], 1);
        if (p < A2_CAP) buf[fb][p] = en;
        else { int sp = atomicAdd(spillcnt, 1); if (sp < SPILLCAP) spill[sp] = en; }
    }
    __syncthreads();

    if (t < FPERC) {                               // thread-per-bucket flush
        int c = bcnt[t]; if (c > A2_CAP) c = A2_CAP;
        if (c) {
            int fg = cb * FPERC + t;
            int g = atomicAdd(&fcnt[fg], c);
            unsigned int* fl = flist + (size_t)fg * FCAP;
            for (int i = 0; i < c; ++i) {
                int pos = g + i;
                unsigned int v = buf[t][i];
                if (pos < FCAP) fl[pos] = v;
                else { int sp = atomicAdd(spillcnt, 1); if (sp < SPILLCAP) spill[sp] = v; }
            }
        }
    }
}

// ===========================================================================
// K3: per fine bin (16 nodes): build 16x16384-bit dedup bitmap in LDS
// (atomicOr -> exact 0/1 adjacency), extract+gather (round-4 proven path,
// now LDS-sourced), fused epilogue. No global bitmap, no 32MiB memset.
// ===========================================================================
__global__ __launch_bounds__(256) void gnn_gather_update(
        const unsigned int* __restrict__ flist, const int* __restrict__ fcnt,
        const unsigned int* __restrict__ spill, const int* __restrict__ spillcnt,
        const float* __restrict__ x, float* __restrict__ out,
        const float* __restrict__ W_agg, const float* __restrict__ b_agg,
        const float* __restrict__ W_upd, const float* __restrict__ b_upd) {
    __shared__ unsigned int sbit[16][512];         // 32 KB
    __shared__ float sWa[D][D + 1], sWu[D][D + 1]; // 8.4 KB
    __shared__ float sbias[D];
    __shared__ float sxn[16][D], smsg[16][D];      // 4 KB
    __shared__ int slist[4][GCAP];                 // 4 KB

    int t = threadIdx.x;
    int fb = blockIdx.x;

    for (int i = t; i < 16 * 512; i += 256) ((unsigned int*)sbit)[i] = 0u;
    for (int i = t; i < D * D; i += 256) {
        sWa[i >> 5][i & 31] = W_agg[i];
        sWu[i >> 5][i & 31] = W_upd[i];
    }
    if (t < D) sbias[t] = b_agg[t] + b_upd[t];
    for (int i = t; i < 16 * D; i += 256)
        ((float*)sxn)[i] = x[(size_t)fb * 16 * D + i];
    __syncthreads();

    int cnt = fcnt[fb]; if (cnt > FCAP) cnt = FCAP;
    const unsigned int* fl = flist + (size_t)fb * FCAP;
    for (int i = t; i < cnt; i += 256) {
        unsigned int en = fl[i];
        int nl = (en >> 14) & 15;
        int nbr = en & 16383;
        atomicOr(&sbit[nl][nbr >> 5], 1u << (nbr & 31));
    }
    int sc = *spillcnt; if (sc > SPILLCAP) sc = SPILLCAP;
    for (int i = t; i < sc; i += 256) {            // exactness safety net (~0)
        unsigned int en = spill[i];
        int node = en >> 14;
        if ((node >> 4) == fb) {
            int nbr = en & 16383;
            atomicOr(&sbit[node & 15][nbr >> 5], 1u << (nbr & 31));
        }
    }
    __syncthreads();

    int wv = t >> 6, lane = t & 63, dim = lane & 31, half = lane >> 5;
    for (int q = 0; q < 4; ++q) {
        int nl = wv * 4 + q;
        unsigned int w[8];
#pragma unroll
        for (int c = 0; c < 8; ++c) w[c] = sbit[nl][c * 64 + lane];
        int myc = 0;
#pragma unroll
        for (int c = 0; c < 8; ++c) myc += __popc(w[c]);
        int pre = myc;
#pragma unroll
        for (int off = 1; off < 64; off <<= 1) {
            int v = __shfl_up(pre, off, 64);
            if (lane >= off) pre += v;
        }
        int total = __shfl(pre, 63, 64);
        pre -= myc;
        float acc = 0.f;
        if (total <= GCAP) {
            int p = pre;
#pragma unroll
            for (int c = 0; c < 8; ++c) {
                unsigned int ww = w[c];
                int bb = (c * 64 + lane) * 32;
                while (ww) { int b = __ffs(ww) - 1; ww &= ww - 1; slist[wv][p++] = bb + b; }
            }
            int j = half;
            for (; j + 8 <= total; j += 8) {
                int c0 = slist[wv][j + 0], c1 = slist[wv][j + 2];
                int c2 = slist[wv][j + 4], c3 = slist[wv][j + 6];
                float v0 = x[(size_t)c0 * D + dim];
                float v1 = x[(size_t)c1 * D + dim];
                float v2 = x[(size_t)c2 * D + dim];
                float v3 = x[(size_t)c3 * D + dim];
                acc += v0; acc += v1; acc += v2; acc += v3;
            }
            for (; j < total; j += 2) acc += x[(size_t)slist[wv][j] * D + dim];
        } else {                                   // exact high-degree fallback
            for (int c = 0; c < 8; ++c) {
                unsigned long long m = __ballot(w[c] != 0);
                while (m) {
                    int l = __ffsll(m) - 1; m &= m - 1;
                    unsigned int ww = __shfl(w[c], l, 64);
                    int bb = (c * 64 + l) * 32;
                    while (ww) { int b = __ffs(ww) - 1; ww &= ww - 1;
                                 acc += x[(size_t)(bb + b) * D + dim]; }
                }
            }
        }
        acc += __shfl_xor(acc, 32, 64);
        if (lane < D) smsg[nl][lane] = acc;
    }
    __syncthreads();

    for (int o = t; o < 16 * D; o += 256) {
        int nl = o >> 5, od = o & 31;
        float r = sbias[od];
#pragma unroll
        for (int k = 0; k < D; ++k)
            r += sxn[nl][k] * sWu[od][k] + smsg[nl][k] * sWa[od][k];
        out[((size_t)fb * 16 + nl) * D + od] = r;
    }
}

// ===========================================================================
// FALLBACK PATH (small ws or N != 16384): hash-dedup + scattered atomics.
// ===========================================================================
#define HASH_BITS 20
#define HASH_SIZE (1u << HASH_BITS)
#define EMPTY_KEY 0xFFFFFFFFu

__global__ void gnn_edge_scatter(const int* __restrict__ src,
                                 const int* __restrict__ dst,
                                 const float* __restrict__ x,
                                 float* __restrict__ msg,
                                 unsigned int* __restrict__ htab, int E, int N) {
    int e = blockIdx.x * blockDim.x + threadIdx.x;
    if (e >= E) return;
    int s = src[e], d = dst[e];
    int a = s < d ? s : d, b = s < d ? d : s;
    unsigned long long key = (unsigned long long)a * N + b;
    unsigned int k32 = (unsigned int)(key & 0xFFFFFFFEu) | 1u;  // never EMPTY
    unsigned int h = ((unsigned int)key * 2654435761u) >> (32 - HASH_BITS);
    bool inserted;
    for (;;) {
        unsigned int prev = atomicCAS(&htab[h], EMPTY_KEY, k32);
        if (prev == EMPTY_KEY) { inserted = true; break; }
        if (prev == k32)       { inserted = false; break; }
        h = (h + 1) & (HASH_SIZE - 1);
    }
    if (!inserted) return;
    const float* xs = x + (size_t)s * D;
    const float* xd = x + (size_t)d * D;
    if (s == d) {
        float* m = msg + (size_t)s * D;
#pragma unroll
        for (int i = 0; i < D; ++i) atomicAdd(&m[i], xs[i]);
    } else {
        float* ms = msg + (size_t)s * D;
        float* md = msg + (size_t)d * D;
#pragma unroll
        for (int i = 0; i < D; ++i) {
            atomicAdd(&ms[i], xd[i]);
            atomicAdd(&md[i], xs[i]);
        }
    }
}

__global__ __launch_bounds__(256) void gnn_update(
        const float* __restrict__ x, float* __restrict__ out,
        const float* __restrict__ W_agg, const float* __restrict__ b_agg,
        const float* __restrict__ W_upd, const float* __restrict__ b_upd) {
    __shared__ float sWa[D][D + 1], sWu[D][D + 1], sb[D];
    __shared__ float sx[8][D], sm[8][D];
    int t = threadIdx.x;
    for (int i = t; i < D * D; i += 256) {
        sWa[i >> 5][i & 31] = W_agg[i];
        sWu[i >> 5][i & 31] = W_upd[i];
    }
    if (t < D) sb[t] = b_agg[t] + b_upd[t];
    int g = t >> 5, o = t & 31;
    size_t node = (size_t)blockIdx.x * 8 + g;
    sx[g][o] = x[node * D + o];
    sm[g][o] = out[node * D + o];
    __syncthreads();
    float acc = sb[o];
#pragma unroll
    for (int k = 0; k < D; ++k)
        acc += sx[g][k] * sWu[o][k] + sm[g][k] * sWa[o][k];
    out[node * D + o] = acc;
}

// ===========================================================================

extern "C" void kernel_launch(void* const* d_in, const int* in_sizes, int n_in,
                              void* d_out, int out_size, void* d_ws, size_t ws_size,
                              hipStream_t stream) {
    const float* x     = (const float*)d_in[0];
    const int*   eidx  = (const int*)d_in[1];
    const float* W_agg = (const float*)d_in[2];
    const float* b_agg = (const float*)d_in[3];
    const float* W_upd = (const float*)d_in[4];
    const float* b_upd = (const float*)d_in[5];
    float* out = (float*)d_out;

    const int E = in_sizes[1] / 2;
    const int N = in_sizes[0] / D;
    const int* src = eidx;
    const int* dst = eidx + E;

    // ws layout: [0,8KB) counters | clist 16MB | flist 16MB | spill 32KB
    char* w = (char*)d_ws;
    int* ccnt = (int*)w;                         // 8 ints
    int* fcnt = (int*)(w + 64);                  // 1024 ints
    int* spillcnt = (int*)(w + 4160);            // 1 int
    unsigned int* clist = (unsigned int*)(w + 8192);
    unsigned int* flist = clist + (size_t)NB_C * CCAP;
    unsigned int* spill = flist + (size_t)NB_F * FCAP;
    size_t need = 8192 + (size_t)NB_C * CCAP * 4 + (size_t)NB_F * FCAP * 4
                + (size_t)SPILLCAP * 4;

    if (N == 16384 && ws_size >= need) {
        hipMemsetAsync(w, 0, 8192, stream);
        gnn_bin_coarse<<<(E + A_EPB - 1) / A_EPB, 256, 0, stream>>>(
            src, dst, E, clist, ccnt, spill, spillcnt);
        gnn_bin_fine<<<NB_C * 64, 256, 0, stream>>>(
            clist, ccnt, flist, fcnt, spill, spillcnt);
        gnn_gather_update<<<NB_F, 256, 0, stream>>>(
            flist, fcnt, spill, spillcnt, x, out, W_agg, b_agg, W_upd, b_upd);
    } else {
        unsigned int* htab = (unsigned int*)d_ws;
        hipMemsetAsync(out, 0, (size_t)N * D * sizeof(float), stream);
        hipMemsetAsync(htab, 0xFF, (size_t)HASH_SIZE * sizeof(unsigned int), stream);
        gnn_edge_scatter<<<(E + 255) / 256, 256, 0, stream>>>(src, dst, x, out,
                                                              htab, E, N);
        gnn_update<<<N / 8, 256, 0, stream>>>(x, out, W_agg, b_agg, W_upd, b_upd);
    }
}

// Round 7
// 147.209 us; speedup vs baseline: 1.2448x; 1.2448x over previous
//
#include <hip/hip_runtime.h>

#define D 32
#define GCAP 256          // per-node neighbor cap for fast extraction path

// ===========================================================================
// K1: set adjacency bits in a 32 MiB N*N bitmap. atomicOr is idempotent ->
// duplicate edges / (a,b)+(b,a) / self-loops all collapse to the exact 0/1
// adjacency semantics of the reference.
// ===========================================================================
__global__ void gnn_edge_bits(const int* __restrict__ src,
                              const int* __restrict__ dst,
                              unsigned int* __restrict__ bm,
                              int E, int wpr) {
    int e = blockIdx.x * blockDim.x + threadIdx.x;
    if (e >= E) return;
    int s = src[e];
    int d = dst[e];
    atomicOr(&bm[(size_t)d * wpr + (s >> 5)], 1u << (s & 31));
    atomicOr(&bm[(size_t)s * wpr + (d >> 5)], 1u << (d & 31));
}

// ===========================================================================
// K2: gather + fused update. 16 nodes/block, 4 nodes/wave. All 4 bitmap rows
// are loaded up-front as uint4 (8x global_load_dwordx4 in flight = 128B/lane)
// to hide HBM latency; extraction via popc+prefix into per-node LDS lists;
// x-gather runs 8 independent L2 loads deep per half-wave.
// ===========================================================================
__global__ __launch_bounds__(256) void gnn_gather_update(
        const unsigned int* __restrict__ bm,
        const float* __restrict__ x,
        float* __restrict__ out,
        const float* __restrict__ W_agg,
        const float* __restrict__ b_agg,
        const float* __restrict__ W_upd,
        const float* __restrict__ b_upd,
        int wpr) {
    __shared__ float sWa[D][D + 1];
    __shared__ float sWu[D][D + 1];
    __shared__ float sbias[D];
    __shared__ float sx[16][D];
    __shared__ float sm[16][D];
    __shared__ int   slist[4][4][GCAP];     // [wave][node-in-wave][idx]

    int t = threadIdx.x;
    for (int i = t; i < D * D; i += 256) {
        sWa[i >> 5][i & 31] = W_agg[i];
        sWu[i >> 5][i & 31] = W_upd[i];
    }
    if (t < D) sbias[t] = b_agg[t] + b_upd[t];
    for (int i = t; i < 16 * D; i += 256)
        ((float*)sx)[i] = x[(size_t)blockIdx.x * 16 * D + i];

    int lane = t & 63;
    int wv   = t >> 6;
    int dim  = lane & 31;
    int half = lane >> 5;
    int nb   = blockIdx.x * 16 + wv * 4;    // this wave's first node

    // ---- prefetch all 4 bitmap rows: 8 x dwordx4 in flight ----
    uint4 q[8];
#pragma unroll
    for (int nn = 0; nn < 4; ++nn) {
        const uint4* row = (const uint4*)(bm + (size_t)(nb + nn) * wpr);
        q[nn * 2 + 0] = row[lane];
        q[nn * 2 + 1] = row[64 + lane];
    }

    float accs[4];
#pragma unroll
    for (int nn = 0; nn < 4; ++nn) {
        unsigned int w[8] = { q[nn*2].x,   q[nn*2].y,   q[nn*2].z,   q[nn*2].w,
                              q[nn*2+1].x, q[nn*2+1].y, q[nn*2+1].z, q[nn*2+1].w };
        int myc = 0;
#pragma unroll
        for (int k = 0; k < 8; ++k) myc += __popc(w[k]);
        int pre = myc;
#pragma unroll
        for (int off = 1; off < 64; off <<= 1) {
            int v = __shfl_up(pre, off, 64);
            if (lane >= off) pre += v;
        }
        int total = __shfl(pre, 63, 64);
        pre -= myc;

        float acc = 0.f;
        if (total <= GCAP) {
            int p = pre;
#pragma unroll
            for (int k = 0; k < 8; ++k) {
                unsigned int ww = w[k];
                // word index: k<4 -> 4*lane+k (first 1KB), else 256+4*lane+k-4
                int widx = (k < 4) ? (4 * lane + k) : (256 + 4 * lane + k - 4);
                int base = widx * 32;
                while (ww) {
                    int b = __ffs(ww) - 1;
                    ww &= ww - 1;
                    slist[wv][nn][p++] = base + b;
                }
            }
            __asm__ __volatile__("s_waitcnt lgkmcnt(0)" ::: "memory");

            const int* sl = slist[wv][nn];
            int j = half;
            for (; j + 16 <= total; j += 16) {
                int c0 = sl[j +  0], c1 = sl[j +  2], c2 = sl[j +  4], c3 = sl[j +  6];
                int c4 = sl[j +  8], c5 = sl[j + 10], c6 = sl[j + 12], c7 = sl[j + 14];
                float v0 = x[(size_t)c0 * D + dim];
                float v1 = x[(size_t)c1 * D + dim];
                float v2 = x[(size_t)c2 * D + dim];
                float v3 = x[(size_t)c3 * D + dim];
                float v4 = x[(size_t)c4 * D + dim];
                float v5 = x[(size_t)c5 * D + dim];
                float v6 = x[(size_t)c6 * D + dim];
                float v7 = x[(size_t)c7 * D + dim];
                acc += v0; acc += v1; acc += v2; acc += v3;
                acc += v4; acc += v5; acc += v6; acc += v7;
            }
            for (; j < total; j += 2)
                acc += x[(size_t)sl[j] * D + dim];
        } else {
            // exact high-degree fallback: serial ballot scan
#pragma unroll
            for (int k = 0; k < 8; ++k) {
                unsigned long long m = __ballot(w[k] != 0);
                while (m) {
                    int l = __ffsll(m) - 1;
                    m &= m - 1;
                    unsigned int ww = __shfl(w[k], l, 64);
                    int widx = (k < 4) ? (4 * l + k) : (256 + 4 * l + k - 4);
                    int base = widx * 32;
                    while (ww) {
                        int b = __ffs(ww) - 1;
                        ww &= ww - 1;
                        acc += x[(size_t)(base + b) * D + dim];
                    }
                }
            }
        }
        accs[nn] = acc;
    }

#pragma unroll
    for (int nn = 0; nn < 4; ++nn) {
        float a = accs[nn] + __shfl_xor(accs[nn], 32, 64);
        if (lane < D) sm[wv * 4 + nn][lane] = a;
    }
    __syncthreads();

    // ---- fused epilogue: out = b + x*W_upd^T + msg*W_agg^T ----
    for (int o = t; o < 16 * D; o += 256) {
        int nl = o >> 5, od = o & 31;
        float r = sbias[od];
#pragma unroll
        for (int k = 0; k < D; ++k)
            r += sx[nl][k] * sWu[od][k] + sm[nl][k] * sWa[od][k];
        out[((size_t)blockIdx.x * 16 + nl) * D + od] = r;
    }
}

// ===========================================================================
// FALLBACK PATH (small ws): hash-dedup + scattered atomics.
// ===========================================================================
#define HASH_BITS 20
#define HASH_SIZE (1u << HASH_BITS)
#define EMPTY_KEY 0xFFFFFFFFu

__global__ void gnn_edge_scatter(const int* __restrict__ src,
                                 const int* __restrict__ dst,
                                 const float* __restrict__ x,
                                 float* __restrict__ msg,
                                 unsigned int* __restrict__ htab, int E, int N) {
    int e = blockIdx.x * blockDim.x + threadIdx.x;
    if (e >= E) return;
    int s = src[e], d = dst[e];
    int a = s < d ? s : d, b = s < d ? d : s;
    unsigned long long key = (unsigned long long)a * N + b;
    unsigned int k32 = (unsigned int)(key & 0xFFFFFFFEu) | 1u;
    unsigned int h = ((unsigned int)key * 2654435761u) >> (32 - HASH_BITS);
    bool inserted;
    for (;;) {
        unsigned int prev = atomicCAS(&htab[h], EMPTY_KEY, k32);
        if (prev == EMPTY_KEY) { inserted = true; break; }
        if (prev == k32)       { inserted = false; break; }
        h = (h + 1) & (HASH_SIZE - 1);
    }
    if (!inserted) return;
    const float* xs = x + (size_t)s * D;
    const float* xd = x + (size_t)d * D;
    if (s == d) {
        float* m = msg + (size_t)s * D;
#pragma unroll
        for (int i = 0; i < D; ++i) atomicAdd(&m[i], xs[i]);
    } else {
        float* ms = msg + (size_t)s * D;
        float* md = msg + (size_t)d * D;
#pragma unroll
        for (int i = 0; i < D; ++i) {
            atomicAdd(&ms[i], xd[i]);
            atomicAdd(&md[i], xs[i]);
        }
    }
}

__global__ __launch_bounds__(256) void gnn_update(
        const float* __restrict__ x, float* __restrict__ out,
        const float* __restrict__ W_agg, const float* __restrict__ b_agg,
        const float* __restrict__ W_upd, const float* __restrict__ b_upd) {
    __shared__ float sWa[D][D + 1], sWu[D][D + 1], sb[D];
    __shared__ float sx[8][D], sm[8][D];
    int t = threadIdx.x;
    for (int i = t; i < D * D; i += 256) {
        sWa[i >> 5][i & 31] = W_agg[i];
        sWu[i >> 5][i & 31] = W_upd[i];
    }
    if (t < D) sb[t] = b_agg[t] + b_upd[t];
    int g = t >> 5, o = t & 31;
    size_t node = (size_t)blockIdx.x * 8 + g;
    sx[g][o] = x[node * D + o];
    sm[g][o] = out[node * D + o];
    __syncthreads();
    float acc = sb[o];
#pragma unroll
    for (int k = 0; k < D; ++k)
        acc += sx[g][k] * sWu[o][k] + sm[g][k] * sWa[o][k];
    out[node * D + o] = acc;
}

// ===========================================================================

extern "C" void kernel_launch(void* const* d_in, const int* in_sizes, int n_in,
                              void* d_out, int out_size, void* d_ws, size_t ws_size,
                              hipStream_t stream) {
    const float* x     = (const float*)d_in[0];
    const int*   eidx  = (const int*)d_in[1];
    const float* W_agg = (const float*)d_in[2];
    const float* b_agg = (const float*)d_in[3];
    const float* W_upd = (const float*)d_in[4];
    const float* b_upd = (const float*)d_in[5];
    float* out = (float*)d_out;

    const int E = in_sizes[1] / 2;
    const int N = in_sizes[0] / D;
    const int* src = eidx;
    const int* dst = eidx + E;

    const int wpr = N >> 5;
    const size_t bm_bytes = (size_t)N * wpr * sizeof(unsigned int);   // 32 MiB

    if ((N & 15) == 0 && ws_size >= bm_bytes) {
        unsigned int* bm = (unsigned int*)d_ws;
        hipMemsetAsync(bm, 0, bm_bytes, stream);
        gnn_edge_bits<<<(E + 255) / 256, 256, 0, stream>>>(src, dst, bm, E, wpr);
        gnn_gather_update<<<N / 16, 256, 0, stream>>>(bm, x, out, W_agg, b_agg,
                                                      W_upd, b_upd, wpr);
    } else {
        unsigned int* htab = (unsigned int*)d_ws;
        hipMemsetAsync(out, 0, (size_t)N * D * sizeof(float), stream);
        hipMemsetAsync(htab, 0xFF, (size_t)HASH_SIZE * sizeof(unsigned int), stream);
        gnn_edge_scatter<<<(E + 255) / 256, 256, 0, stream>>>(src, dst, x, out,
                                                              htab, E, N);
        gnn_update<<<N / 8, 256, 0, stream>>>(x, out, W_agg, b_agg, W_upd, b_upd);
    }
}